// Round 2
// baseline (1843.697 us; speedup 1.0000x reference)
//
#include <hip/hip_runtime.h>

#define HW 65536
#define IMG 256
#define NB 4

__device__ __forceinline__ float hsum4(float4 v) { return v.x + v.y + v.z + v.w; }

// ---------------- 1x1 conv (pointwise), X tile staged in LDS ----------------
// grid: (HW/256, 1), block 256. Each wave handles wave-uniform sets of 8 out-channels.
// All pointers pre-offset for the batch by the host.
template<int Ci, int Co, bool ACC>
__global__ __launch_bounds__(256)
void conv1x1_kernel(const float* __restrict__ in, int in_ctot, int ci_off,
                    const float* __restrict__ w, int w_rstride,
                    const float* __restrict__ bias, float* __restrict__ out)
{
    __shared__ float4 Xs[Ci * 64];   // Ci*1KB  (<=64KB)
    const int q0 = blockIdx.x * 64;  // float4 (quad) offset within image
    const float4* in4 = (const float4*)in + (size_t)ci_off * (HW/4) + q0;
    for (int idx = threadIdx.x; idx < Ci * 64; idx += 256) {
        int ci = idx >> 6, j = idx & 63;
        Xs[idx] = in4[(size_t)ci * (HW/4) + j];
    }
    __syncthreads();
    const int wv = __builtin_amdgcn_readfirstlane((int)(threadIdx.x >> 6));
    const int j  = threadIdx.x & 63;
    float4* out4 = (float4*)out + q0 + j;
    #pragma unroll
    for (int cb = 0; cb < Co/32; ++cb) {
        const int co0 = cb*32 + wv*8;
        float4 acc[8];
        #pragma unroll
        for (int k = 0; k < 8; ++k) {
            float bv = bias ? bias[co0+k] : 0.f;
            acc[k] = make_float4(bv, bv, bv, bv);
        }
        #pragma unroll 4
        for (int ci = 0; ci < Ci; ++ci) {
            float4 x = Xs[ci*64 + j];
            #pragma unroll
            for (int k = 0; k < 8; ++k) {
                float wk = w[(co0+k)*w_rstride + ci];
                acc[k].x = fmaf(wk, x.x, acc[k].x);
                acc[k].y = fmaf(wk, x.y, acc[k].y);
                acc[k].z = fmaf(wk, x.z, acc[k].z);
                acc[k].w = fmaf(wk, x.w, acc[k].w);
            }
        }
        #pragma unroll
        for (int k = 0; k < 8; ++k) {
            float4 r = acc[k];
            if (ACC) {
                float4 prev = out4[(size_t)(co0+k) * (HW/4)];
                r.x += prev.x; r.y += prev.y; r.z += prev.z; r.w += prev.w;
            }
            out4[(size_t)(co0+k) * (HW/4)] = r;
        }
    }
}

// ---------------- depthwise conv (5x5 pad2, or 3x3 dil3 pad3) ----------------
// grid: (W/64, H/16, C), block 256; each thread 4 px of one row. Pointers pre-offset per batch.
template<int TAPS, int DIL>
__global__ __launch_bounds__(256)
void dwconv_kernel(const float* __restrict__ in, const float* __restrict__ wt,
                   const float* __restrict__ bias, float* __restrict__ out)
{
    constexpr int HALO = DIL * (TAPS/2);
    constexpr int TW = 64, TH = 16;
    constexpr int LW = TW + 2*HALO;
    constexpr int LH = TH + 2*HALO;
    constexpr int RS = (LW + 3) & ~3;   // 16B-aligned row stride
    __shared__ float Xs[LH * RS];
    const int c = blockIdx.z;
    const int x0 = blockIdx.x * TW, y0 = blockIdx.y * TH;
    const float* ip = in + (size_t)c * HW;
    float wk[TAPS*TAPS];
    #pragma unroll
    for (int i = 0; i < TAPS*TAPS; ++i) wk[i] = wt[c*TAPS*TAPS + i];
    const float bv = bias[c];
    for (int idx = threadIdx.x; idx < LH*LW; idx += 256) {
        int ly = idx / LW, lx = idx - ly*LW;
        int gy = y0 + ly - HALO, gx = x0 + lx - HALO;
        float v = 0.f;
        if (gy >= 0 && gy < IMG && gx >= 0 && gx < IMG)
            v = ip[gy*IMG + gx];
        Xs[ly*RS + lx] = v;
    }
    __syncthreads();
    const int qx = (threadIdx.x & 15) * 4;
    const int ly = threadIdx.x >> 4;
    float o0 = bv, o1 = bv, o2 = bv, o3 = bv;
    #pragma unroll
    for (int ky = 0; ky < TAPS; ++ky) {
        const float* row = &Xs[(ly + ky*DIL)*RS + qx];
        float win[(TAPS-1)*DIL + 4];
        #pragma unroll
        for (int i = 0; i < (TAPS-1)*DIL + 4; ++i) win[i] = row[i];
        #pragma unroll
        for (int kx = 0; kx < TAPS; ++kx) {
            float wv_ = wk[ky*TAPS + kx];
            o0 = fmaf(wv_, win[kx*DIL + 0], o0);
            o1 = fmaf(wv_, win[kx*DIL + 1], o1);
            o2 = fmaf(wv_, win[kx*DIL + 2], o2);
            o3 = fmaf(wv_, win[kx*DIL + 3], o3);
        }
    }
    *(float4*)(out + (size_t)c * HW + (size_t)(y0 + ly)*IMG + x0 + qx) =
        make_float4(o0, o1, o2, o3);
}

// ---------------- GroupNorm(2) stats: sum / sumsq per group ----------------
// grid: (Cg*HW/16384, 2, 1), block 256; each thread 16 float4. stats = 4 floats [g*2+{0,1}].
__global__ __launch_bounds__(256)
void gn_stats_kernel(const float* __restrict__ in, float* __restrict__ stats, int Cg)
{
    const int g = blockIdx.y;
    const float4* p = (const float4*)(in + (size_t)g * Cg * HW)
                      + (size_t)blockIdx.x * 4096;
    float s = 0.f, ss = 0.f;
    #pragma unroll
    for (int i = 0; i < 16; ++i) {
        float4 v = p[threadIdx.x + i*256];
        s  += v.x + v.y + v.z + v.w;
        ss += v.x*v.x + v.y*v.y + v.z*v.z + v.w*v.w;
    }
    #pragma unroll
    for (int o = 32; o; o >>= 1) { s += __shfl_down(s, o, 64); ss += __shfl_down(ss, o, 64); }
    __shared__ float red[8];
    if ((threadIdx.x & 63) == 0) { red[(threadIdx.x >> 6)*2] = s; red[(threadIdx.x >> 6)*2+1] = ss; }
    __syncthreads();
    if (threadIdx.x == 0) {
        atomicAdd(&stats[g*2+0], red[0]+red[2]+red[4]+red[6]);
        atomicAdd(&stats[g*2+1], red[1]+red[3]+red[5]+red[7]);
    }
}

// ---------------- GN apply + leaky_relu(0.2) + per-channel sumsq (for l2norm) ----------------
// grid: (HW/1024, C, 1), block 256, in-place.
__global__ __launch_bounds__(256)
void gn_apply_kernel(float* __restrict__ xio, const float* __restrict__ stats,
                     const float* __restrict__ gamma, const float* __restrict__ beta,
                     float* __restrict__ sumsq, int C)
{
    const int c = blockIdx.y;
    const int Cg = C >> 1;
    const int g = (c >= Cg) ? 1 : 0;
    const float N = (float)Cg * (float)HW;
    const float sm = stats[g*2+0], sq = stats[g*2+1];
    const float mean = sm / N;
    const float rstd = rsqrtf(sq / N - mean*mean + 1e-5f);
    const float A  = gamma[c] * rstd;
    const float Bc = beta[c] - mean * A;
    float4* p = (float4*)(xio + (size_t)c * HW) + blockIdx.x*256 + threadIdx.x;
    float4 v = *p;
    v.x = v.x*A + Bc; v.x = (v.x >= 0.f) ? v.x : 0.2f*v.x;
    v.y = v.y*A + Bc; v.y = (v.y >= 0.f) ? v.y : 0.2f*v.y;
    v.z = v.z*A + Bc; v.z = (v.z >= 0.f) ? v.z : 0.2f*v.z;
    v.w = v.w*A + Bc; v.w = (v.w >= 0.f) ? v.w : 0.2f*v.w;
    *p = v;
    float ss = v.x*v.x + v.y*v.y + v.z*v.z + v.w*v.w;
    #pragma unroll
    for (int o = 32; o; o >>= 1) ss += __shfl_down(ss, o, 64);
    __shared__ float red[4];
    if ((threadIdx.x & 63) == 0) red[threadIdx.x >> 6] = ss;
    __syncthreads();
    if (threadIdx.x == 0 && c < 64)
        atomicAdd(&sumsq[c], red[0]+red[1]+red[2]+red[3]);
}

// ---------------- attention raw dots: attn_raw[h,c,d] = sum_n q_c k_d ----------------
// grid: (128 chunks of 512px, H=4, 1), block 256. LDS transposed [t][c] for conflict-free b128.
__global__ __launch_bounds__(256)
void attn_dot_kernel(const float* __restrict__ q, const float* __restrict__ kv,
                     float* __restrict__ attn_raw)
{
    __shared__ float4 qs[128*16], ks[128*16];   // 32KB each
    const int h = blockIdx.y;
    const int t0 = blockIdx.x * 128;
    const float4* q4 = (const float4*)q  + (size_t)(h*16) * (HW/4) + t0;
    const float4* k4 = (const float4*)kv + (size_t)(h*16) * (HW/4) + t0;
    for (int idx = threadIdx.x; idx < 2048; idx += 256) {
        int cc = idx & 15, t = idx >> 4;
        qs[idx] = q4[(size_t)cc * (HW/4) + t];
        ks[idx] = k4[(size_t)cc * (HW/4) + t];
    }
    __syncthreads();
    const int p   = threadIdx.x & 63;
    const int sub = threadIdx.x >> 6;           // 4 sub-chunks of 32 quads
    const int c0 = (p >> 3) << 1, d0 = (p & 7) << 1;
    float4 a00 = make_float4(0,0,0,0), a01 = a00, a10 = a00, a11 = a00;
    #pragma unroll
    for (int i = 0; i < 32; ++i) {
        int t = sub*32 + i;
        float4 qa = qs[t*16 + c0], qb = qs[t*16 + c0 + 1];
        float4 ka = ks[t*16 + d0], kb = ks[t*16 + d0 + 1];
        a00.x = fmaf(qa.x, ka.x, a00.x); a00.y = fmaf(qa.y, ka.y, a00.y);
        a00.z = fmaf(qa.z, ka.z, a00.z); a00.w = fmaf(qa.w, ka.w, a00.w);
        a01.x = fmaf(qa.x, kb.x, a01.x); a01.y = fmaf(qa.y, kb.y, a01.y);
        a01.z = fmaf(qa.z, kb.z, a01.z); a01.w = fmaf(qa.w, kb.w, a01.w);
        a10.x = fmaf(qb.x, ka.x, a10.x); a10.y = fmaf(qb.y, ka.y, a10.y);
        a10.z = fmaf(qb.z, ka.z, a10.z); a10.w = fmaf(qb.w, ka.w, a10.w);
        a11.x = fmaf(qb.x, kb.x, a11.x); a11.y = fmaf(qb.y, kb.y, a11.y);
        a11.z = fmaf(qb.z, kb.z, a11.z); a11.w = fmaf(qb.w, kb.w, a11.w);
    }
    float* ar = attn_raw + (size_t)(h*16) * 16;
    atomicAdd(&ar[(c0  )*16 + d0  ], hsum4(a00));
    atomicAdd(&ar[(c0  )*16 + d0+1], hsum4(a01));
    atomicAdd(&ar[(c0+1)*16 + d0  ], hsum4(a10));
    atomicAdd(&ar[(c0+1)*16 + d0+1], hsum4(a11));
}

// ---------------- softmax over d with l2-norm scaling + temperature ----------------
// grid: 4 (heads), block 256 = 16x16.
__global__ __launch_bounds__(256)
void attn_softmax_kernel(const float* __restrict__ attn_raw,
                         const float* __restrict__ sumsq_q, const float* __restrict__ sumsq_k,
                         const float* __restrict__ temp, float* __restrict__ attn)
{
    const int h = blockIdx.x;
    const int c = threadIdx.x >> 4, d = threadIdx.x & 15;
    const float nq = fmaxf(sqrtf(sumsq_q[h*16 + c]), 1e-12f);
    const float nk = fmaxf(sqrtf(sumsq_k[h*16 + d]), 1e-12f);
    float logit = attn_raw[(h*16 + c)*16 + d] / (nq * nk) * temp[h];
    float m = logit;
    #pragma unroll
    for (int o = 8; o; o >>= 1) m = fmaxf(m, __shfl_xor(m, o, 16));
    float e = expf(logit - m);
    float s = e;
    #pragma unroll
    for (int o = 8; o; o >>= 1) s += __shfl_xor(s, o, 16);
    attn[(h*16 + c)*16 + d] = e / s;
}

// ---------------- fold proj into per-batch 64x64 matrix: M = proj . blockdiag(attn) ----------------
// grid: 1, block 256.
__global__ __launch_bounds__(256)
void build_m_kernel(const float* __restrict__ attn, const float* __restrict__ proj_w,
                    float* __restrict__ M)
{
    for (int i = threadIdx.x; i < 4096; i += 256) {
        int co = i >> 6, ci = i & 63;
        int h = ci >> 4, d = ci & 15;
        float s = 0.f;
        #pragma unroll
        for (int cc = 0; cc < 16; ++cc)
            s += proj_w[co*64 + h*16 + cc] * attn[(h*16 + cc)*16 + d];
        M[i] = s;
    }
}

extern "C" void kernel_launch(void* const* d_in, const int* in_sizes, int n_in,
                              void* d_out, int out_size, void* d_ws, size_t ws_size,
                              hipStream_t stream)
{
    const float* x       = (const float*)d_in[0];
    const float* y       = (const float*)d_in[1];
    const float* kv_w    = (const float*)d_in[2];
    const float* q_w     = (const float*)d_in[3];
    const float* proj_w  = (const float*)d_in[4];
    const float* kv_c0_w = (const float*)d_in[5];
    const float* kv_c0_b = (const float*)d_in[6];
    const float* kv_cs_w = (const float*)d_in[7];
    const float* kv_cs_b = (const float*)d_in[8];
    const float* kv_c1_w = (const float*)d_in[9];
    const float* kv_c1_b = (const float*)d_in[10];
    const float* kv_gn_g = (const float*)d_in[11];
    const float* kv_gn_b = (const float*)d_in[12];
    const float* q_c0_w  = (const float*)d_in[13];
    const float* q_c0_b  = (const float*)d_in[14];
    const float* q_cs_w  = (const float*)d_in[15];
    const float* q_cs_b  = (const float*)d_in[16];
    const float* q_c1_w  = (const float*)d_in[17];
    const float* q_c1_b  = (const float*)d_in[18];
    const float* q_gn_g  = (const float*)d_in[19];
    const float* q_gn_b  = (const float*)d_in[20];
    const float* temp    = (const float*)d_in[21];

    // ---- workspace layout: small area (100 KB) then two 32 MiB ping-pong buffers ----
    float* ws       = (float*)d_ws;
    float* statsKV  = ws;            // 4 per batch  -> 16
    float* statsQ   = ws + 16;       // 4 per batch  -> 16
    float* sumsq_k  = ws + 32;       // 64 per batch -> 256
    float* sumsq_q  = ws + 288;      // 64 per batch -> 256
    float* attn_raw = ws + 544;      // 1024 per batch -> 4096
    float* attn     = ws + 4640;     // 1024 per batch -> 4096
    float* Mw       = ws + 8736;     // 4096 per batch -> 16384  (ends at 25120 floats)
    float* bufA = (float*)((char*)d_ws + 131072);     // 128*HW floats = 32 MiB
    float* bufB = bufA + (size_t)128 * HW;            // 128*HW floats = 32 MiB
    float* qA = bufA;                                 // 64*HW (reuses bufA after kv chain)
    float* qB = bufA + (size_t)64 * HW;
    float* outp = (float*)d_out;

    hipMemsetAsync(d_ws, 0, 102400, stream);

    dim3 blk(256);
    for (int b = 0; b < NB; ++b) {
        const float* xb = x + (size_t)b * 64 * HW;
        const float* yb = y + (size_t)b * 64 * HW;
        float* ob = outp + (size_t)b * 64 * HW;
        float* stK = statsKV + b*4;
        float* stQ = statsQ + b*4;
        float* ssk = sumsq_k + b*64;
        float* ssq = sumsq_q + b*64;
        float* arw = attn_raw + b*1024;
        float* atn = attn + b*1024;
        float* Mb  = Mw + b*4096;

        // ---- kv chain: y -> 1x1(64->128) -> dw5x5 -> dw3x3d3 -> 1x1(128->128)+b -> GN+leaky ----
        conv1x1_kernel<64,128,false><<<dim3(256), blk, 0, stream>>>(yb, 64, 0, kv_w, 64, nullptr, bufA);
        dwconv_kernel<5,1><<<dim3(4,16,128), blk, 0, stream>>>(bufA, kv_c0_w, kv_c0_b, bufB);
        dwconv_kernel<3,3><<<dim3(4,16,128), blk, 0, stream>>>(bufB, kv_cs_w, kv_cs_b, bufA);
        conv1x1_kernel<64,128,false><<<dim3(256), blk, 0, stream>>>(bufA, 128, 0,  kv_c1_w,      128, kv_c1_b, bufB);
        conv1x1_kernel<64,128,true ><<<dim3(256), blk, 0, stream>>>(bufA, 128, 64, kv_c1_w + 64, 128, nullptr, bufB);
        gn_stats_kernel<<<dim3(256,2), blk, 0, stream>>>(bufB, stK, 64);
        gn_apply_kernel<<<dim3(64,128), blk, 0, stream>>>(bufB, stK, kv_gn_g, kv_gn_b, ssk, 128);

        // ---- q chain: x -> 1x1(64->64) -> dw5x5 -> dw3x3d3 -> 1x1(64->64)+b -> GN+leaky ----
        // (reuses bufA region, which is dead after the kv 1x1 above)
        conv1x1_kernel<64,64,false><<<dim3(256), blk, 0, stream>>>(xb, 64, 0, q_w, 64, nullptr, qA);
        dwconv_kernel<5,1><<<dim3(4,16,64), blk, 0, stream>>>(qA, q_c0_w, q_c0_b, qB);
        dwconv_kernel<3,3><<<dim3(4,16,64), blk, 0, stream>>>(qB, q_cs_w, q_cs_b, qA);
        conv1x1_kernel<64,64,false><<<dim3(256), blk, 0, stream>>>(qA, 64, 0, q_c1_w, 64, q_c1_b, qB);
        gn_stats_kernel<<<dim3(128,2), blk, 0, stream>>>(qB, stQ, 32);
        gn_apply_kernel<<<dim3(64,64), blk, 0, stream>>>(qB, stQ, q_gn_g, q_gn_b, ssq, 64);

        // ---- attention (16x16 per head) + proj fold ----
        attn_dot_kernel<<<dim3(128,4), blk, 0, stream>>>(qB, bufB, arw);
        attn_softmax_kernel<<<dim3(4), blk, 0, stream>>>(arw, ssq, ssk, temp, atn);
        build_m_kernel<<<dim3(1), blk, 0, stream>>>(atn, proj_w, Mb);

        // ---- out = M @ v  (v = kv channels 64..127), fused attn@v + proj ----
        conv1x1_kernel<64,64,false><<<dim3(256), blk, 0, stream>>>(bufB, 128, 64, Mb, 64, nullptr, ob);
    }
}

// Round 3
// 1244.924 us; speedup vs baseline: 1.4810x; 1.4810x over previous
//
#include <hip/hip_runtime.h>

#define HW 65536
#define IMG 256

#if defined(__has_builtin)
# if __has_builtin(__builtin_amdgcn_global_load_lds)
#  define HAVE_GLL 1
# endif
#endif

__device__ __forceinline__ float hsum4(float4 v) { return v.x + v.y + v.z + v.w; }

// ---------------- 1x1 conv, CO=64, K-loop over 32-channel LDS chunks ----------------
// grid: (256 pixel-tiles, nb), block 256. Wave wv owns co0=wv*16 (wave-uniform -> scalar weights).
// stats != null: fused GroupNorm partial sum/sumsq (pre-norm values) via atomics.
template<int CIT>
__global__ __launch_bounds__(256)
void conv1x1_v2(const float* __restrict__ in, int in_cs,
                const float* __restrict__ w, int w_bstride,
                const float* __restrict__ bias,
                float* __restrict__ out, int out_cs, int out_coff,
                float* __restrict__ stats, int gsel)
{
    __shared__ float4 Xs[32 * 64];   // 32 KiB
    const int b  = blockIdx.y;
    const int q0 = blockIdx.x * 64;  // quad offset in image
    const int j  = threadIdx.x & 63;
    const int wv = __builtin_amdgcn_readfirstlane((int)(threadIdx.x >> 6));
    const int co0 = wv * 16;
    const float4* in4 = (const float4*)in + (size_t)b * in_cs * (HW/4) + q0;
    const float* wb = w + (size_t)b * w_bstride;

    float4 acc[16];
    #pragma unroll
    for (int k = 0; k < 16; ++k) {
        float bv = bias ? bias[co0 + k] : 0.f;
        acc[k] = make_float4(bv, bv, bv, bv);
    }

    #pragma unroll
    for (int kc = 0; kc < CIT/32; ++kc) {
        #pragma unroll
        for (int it = 0; it < 8; ++it) {
            const int row = wv*8 + it;   // chunk-local ci
            const float4* src = in4 + (size_t)(kc*32 + row) * (HW/4) + j;
#ifdef HAVE_GLL
            __builtin_amdgcn_global_load_lds(
                (const __attribute__((address_space(1))) void*)src,
                (__attribute__((address_space(3))) void*)&Xs[row*64],
                16, 0, 0);
#else
            Xs[row*64 + j] = *src;
#endif
        }
        __syncthreads();
        #pragma unroll 4
        for (int ci = 0; ci < 32; ++ci) {
            float4 x = Xs[ci*64 + j];
            const float* wr = wb + (size_t)(kc*32 + ci);
            #pragma unroll
            for (int k = 0; k < 16; ++k) {
                float wk = wr[(size_t)(co0 + k) * CIT];
                acc[k].x = fmaf(wk, x.x, acc[k].x);
                acc[k].y = fmaf(wk, x.y, acc[k].y);
                acc[k].z = fmaf(wk, x.z, acc[k].z);
                acc[k].w = fmaf(wk, x.w, acc[k].w);
            }
        }
        __syncthreads();
    }

    if (stats) {
        float s = 0.f, ss = 0.f;
        #pragma unroll
        for (int k = 0; k < 16; ++k) {
            s  += acc[k].x + acc[k].y + acc[k].z + acc[k].w;
            ss += acc[k].x*acc[k].x + acc[k].y*acc[k].y
                + acc[k].z*acc[k].z + acc[k].w*acc[k].w;
        }
        #pragma unroll
        for (int o = 32; o; o >>= 1) { s += __shfl_down(s, o, 64); ss += __shfl_down(ss, o, 64); }
        if (j == 0) {
            const int g = (gsel < 0) ? (co0 >= 32 ? 1 : 0) : 0;
            float* st = stats + (size_t)b*4 + g*2;
            atomicAdd(st,     s);
            atomicAdd(st + 1, ss);
        }
    }

    float4* out4 = (float4*)out + ((size_t)b * out_cs + out_coff) * (HW/4) + q0 + j;
    #pragma unroll
    for (int k = 0; k < 16; ++k)
        out4[(size_t)(co0 + k) * (HW/4)] = acc[k];
}

// ---------------- depthwise conv (5x5 pad2 / 3x3 dil3 pad3), 64 channels per dispatch ----------------
// grid: (4, 16, nb*64), block 256; thread computes 4 px of one row.
template<int TAPS, int DIL>
__global__ __launch_bounds__(256)
void dwconv_v2(const float* __restrict__ in, int in_cs, int in_coff,
               const float* __restrict__ wt, const float* __restrict__ bias, int w_coff,
               float* __restrict__ out, int out_cs, int out_coff)
{
    constexpr int HALO = DIL * (TAPS/2);
    constexpr int TW = 64, TH = 16;
    constexpr int LW = TW + 2*HALO;
    constexpr int LH = TH + 2*HALO;
    constexpr int RS = (LW + 3) & ~3;
    __shared__ float Xs[LH * RS];
    const int z = blockIdx.z;
    const int c = z & 63, b = z >> 6;
    const int x0 = blockIdx.x * TW, y0 = blockIdx.y * TH;
    const float* ip = in + ((size_t)b*in_cs + in_coff + c) * HW;
    const int cw = w_coff + c;
    float wk[TAPS*TAPS];
    #pragma unroll
    for (int i = 0; i < TAPS*TAPS; ++i) wk[i] = wt[cw*TAPS*TAPS + i];
    const float bv = bias[cw];
    for (int idx = threadIdx.x; idx < LH*LW; idx += 256) {
        int ly = idx / LW, lx = idx - ly*LW;
        int gy = y0 + ly - HALO, gx = x0 + lx - HALO;
        float v = 0.f;
        if (gy >= 0 && gy < IMG && gx >= 0 && gx < IMG)
            v = ip[gy*IMG + gx];
        Xs[ly*RS + lx] = v;
    }
    __syncthreads();
    const int qx = (threadIdx.x & 15) * 4;
    const int ly = threadIdx.x >> 4;
    float o0 = bv, o1 = bv, o2 = bv, o3 = bv;
    #pragma unroll
    for (int ky = 0; ky < TAPS; ++ky) {
        const float* row = &Xs[(ly + ky*DIL)*RS + qx];
        float win[(TAPS-1)*DIL + 4];
        #pragma unroll
        for (int i = 0; i < (TAPS-1)*DIL + 4; ++i) win[i] = row[i];
        #pragma unroll
        for (int kx = 0; kx < TAPS; ++kx) {
            float wv_ = wk[ky*TAPS + kx];
            o0 = fmaf(wv_, win[kx*DIL + 0], o0);
            o1 = fmaf(wv_, win[kx*DIL + 1], o1);
            o2 = fmaf(wv_, win[kx*DIL + 2], o2);
            o3 = fmaf(wv_, win[kx*DIL + 3], o3);
        }
    }
    *(float4*)(out + ((size_t)b*out_cs + out_coff + c) * HW + (size_t)(y0 + ly)*IMG + x0 + qx) =
        make_float4(o0, o1, o2, o3);
}

// ---------------- GN apply + leaky_relu(0.2) + optional per-channel sumsq ----------------
// grid: (64, 64, nb), block 256; buffer is 64 ch/batch, in-place.
__global__ __launch_bounds__(256)
void gn_apply_v2(float* __restrict__ xio,
                 const float* __restrict__ stats,
                 const float* __restrict__ gamma, const float* __restrict__ beta,
                 float* __restrict__ sumsq, int gdiv, float Nf)
{
    const int c = blockIdx.y, b = blockIdx.z;
    const int g = (c >= gdiv) ? 1 : 0;
    const float* st = stats + (size_t)b*4 + g*2;
    const float mean = st[0] / Nf;
    const float rstd = rsqrtf(st[1]/Nf - mean*mean + 1e-5f);
    const float A  = gamma[c] * rstd;
    const float Bc = beta[c] - mean * A;
    float4* p = (float4*)(xio + ((size_t)b*64 + c) * HW) + blockIdx.x*256 + threadIdx.x;
    float4 v = *p;
    v.x = v.x*A + Bc; v.x = (v.x >= 0.f) ? v.x : 0.2f*v.x;
    v.y = v.y*A + Bc; v.y = (v.y >= 0.f) ? v.y : 0.2f*v.y;
    v.z = v.z*A + Bc; v.z = (v.z >= 0.f) ? v.z : 0.2f*v.z;
    v.w = v.w*A + Bc; v.w = (v.w >= 0.f) ? v.w : 0.2f*v.w;
    *p = v;
    if (sumsq) {
        float ss = v.x*v.x + v.y*v.y + v.z*v.z + v.w*v.w;
        #pragma unroll
        for (int o = 32; o; o >>= 1) ss += __shfl_down(ss, o, 64);
        __shared__ float red[4];
        if ((threadIdx.x & 63) == 0) red[threadIdx.x >> 6] = ss;
        __syncthreads();
        if (threadIdx.x == 0)
            atomicAdd(&sumsq[b*64 + c], red[0]+red[1]+red[2]+red[3]);
    }
}

// ---------------- attention raw dots ----------------
// grid: (128, 4, nb), block 256. LDS transposed [t][c] for conflict-free b128 reads.
__global__ __launch_bounds__(256)
void attn_dot_v2(const float* __restrict__ q, const float* __restrict__ k,
                 float* __restrict__ attn_raw)
{
    __shared__ float4 qs[2048], ks[2048];   // 32 KiB each
    const int h = blockIdx.y, b = blockIdx.z;
    const int t0 = blockIdx.x * 128;
    const float4* q4 = (const float4*)q + ((size_t)b*64 + h*16) * (HW/4) + t0;
    const float4* k4 = (const float4*)k + ((size_t)b*64 + h*16) * (HW/4) + t0;
    for (int idx = threadIdx.x; idx < 2048; idx += 256) {
        int cc = idx & 15, t = idx >> 4;
        qs[idx] = q4[(size_t)cc * (HW/4) + t];
        ks[idx] = k4[(size_t)cc * (HW/4) + t];
    }
    __syncthreads();
    const int p   = threadIdx.x & 63;
    const int sub = threadIdx.x >> 6;
    const int c0 = (p >> 3) << 1, d0 = (p & 7) << 1;
    float4 a00 = make_float4(0,0,0,0), a01 = a00, a10 = a00, a11 = a00;
    #pragma unroll
    for (int i = 0; i < 32; ++i) {
        int t = sub*32 + i;
        float4 qa = qs[t*16 + c0], qb = qs[t*16 + c0 + 1];
        float4 ka = ks[t*16 + d0], kb = ks[t*16 + d0 + 1];
        a00.x = fmaf(qa.x, ka.x, a00.x); a00.y = fmaf(qa.y, ka.y, a00.y);
        a00.z = fmaf(qa.z, ka.z, a00.z); a00.w = fmaf(qa.w, ka.w, a00.w);
        a01.x = fmaf(qa.x, kb.x, a01.x); a01.y = fmaf(qa.y, kb.y, a01.y);
        a01.z = fmaf(qa.z, kb.z, a01.z); a01.w = fmaf(qa.w, kb.w, a01.w);
        a10.x = fmaf(qb.x, ka.x, a10.x); a10.y = fmaf(qb.y, ka.y, a10.y);
        a10.z = fmaf(qb.z, ka.z, a10.z); a10.w = fmaf(qb.w, ka.w, a10.w);
        a11.x = fmaf(qb.x, kb.x, a11.x); a11.y = fmaf(qb.y, kb.y, a11.y);
        a11.z = fmaf(qb.z, kb.z, a11.z); a11.w = fmaf(qb.w, kb.w, a11.w);
    }
    float* ar = attn_raw + ((size_t)b*4 + h) * 256;
    atomicAdd(&ar[(c0  )*16 + d0  ], hsum4(a00));
    atomicAdd(&ar[(c0  )*16 + d0+1], hsum4(a01));
    atomicAdd(&ar[(c0+1)*16 + d0  ], hsum4(a10));
    atomicAdd(&ar[(c0+1)*16 + d0+1], hsum4(a11));
}

// ---------------- softmax with l2-norm scaling + temperature ----------------
// grid: (4, nb), block 256 = 16x16.
__global__ __launch_bounds__(256)
void attn_softmax_v2(const float* __restrict__ attn_raw,
                     const float* __restrict__ ssq, const float* __restrict__ ssk,
                     const float* __restrict__ temp, float* __restrict__ attn)
{
    const int h = blockIdx.x, b = blockIdx.y;
    const int c = threadIdx.x >> 4, d = threadIdx.x & 15;
    const float nq = fmaxf(sqrtf(ssq[b*64 + h*16 + c]), 1e-12f);
    const float nk = fmaxf(sqrtf(ssk[b*64 + h*16 + d]), 1e-12f);
    float logit = attn_raw[((size_t)b*4 + h)*256 + c*16 + d] / (nq * nk) * temp[h];
    float m = logit;
    #pragma unroll
    for (int o = 8; o; o >>= 1) m = fmaxf(m, __shfl_xor(m, o, 16));
    float e = expf(logit - m);
    float s = e;
    #pragma unroll
    for (int o = 8; o; o >>= 1) s += __shfl_xor(s, o, 16);
    attn[((size_t)b*4 + h)*256 + c*16 + d] = e / s;
}

// ---------------- M[b] = proj . blockdiag(attn[b]) ----------------
// grid: nb, block 256.
__global__ __launch_bounds__(256)
void build_m_v2(const float* __restrict__ attn, const float* __restrict__ proj_w,
                float* __restrict__ M)
{
    const int b = blockIdx.x;
    for (int i = threadIdx.x; i < 4096; i += 256) {
        int co = i >> 6, ci = i & 63;
        int h = ci >> 4, d = ci & 15;
        float s = 0.f;
        #pragma unroll
        for (int cc = 0; cc < 16; ++cc)
            s += proj_w[co*64 + h*16 + cc] * attn[((size_t)b*4 + h)*256 + cc*16 + d];
        M[(size_t)b*4096 + i] = s;
    }
}

extern "C" void kernel_launch(void* const* d_in, const int* in_sizes, int n_in,
                              void* d_out, int out_size, void* d_ws, size_t ws_size,
                              hipStream_t stream)
{
    const float* x       = (const float*)d_in[0];
    const float* y       = (const float*)d_in[1];
    const float* kv_w    = (const float*)d_in[2];
    const float* q_w     = (const float*)d_in[3];
    const float* proj_w  = (const float*)d_in[4];
    const float* kv_c0_w = (const float*)d_in[5];
    const float* kv_c0_b = (const float*)d_in[6];
    const float* kv_cs_w = (const float*)d_in[7];
    const float* kv_cs_b = (const float*)d_in[8];
    const float* kv_c1_w = (const float*)d_in[9];
    const float* kv_c1_b = (const float*)d_in[10];
    const float* kv_gn_g = (const float*)d_in[11];
    const float* kv_gn_b = (const float*)d_in[12];
    const float* q_c0_w  = (const float*)d_in[13];
    const float* q_c0_b  = (const float*)d_in[14];
    const float* q_cs_w  = (const float*)d_in[15];
    const float* q_cs_b  = (const float*)d_in[16];
    const float* q_c1_w  = (const float*)d_in[17];
    const float* q_c1_b  = (const float*)d_in[18];
    const float* q_gn_g  = (const float*)d_in[19];
    const float* q_gn_b  = (const float*)d_in[20];
    const float* temp    = (const float*)d_in[21];

    float* ws       = (float*)d_ws;
    float* statsKV  = ws;            // 4/batch  -> 16
    float* statsQ   = ws + 16;
    float* sumsq_k  = ws + 32;       // 64/batch -> 256
    float* sumsq_q  = ws + 288;
    float* attn_raw = ws + 544;      // 1024/batch -> 4096
    float* attn     = ws + 4640;
    float* Mw       = ws + 8736;     // 4096/batch -> 16384 (end 25120)
    float* big      = (float*)((char*)d_ws + 131072);

    // per-batch big-buffer need: H1 = 128*HW, H2 = 64*HW floats  (48 MiB)
    const size_t perb_bytes = (size_t)192 * HW * 4;
    int nb = 1;
    if      (ws_size >= 131072 + 4*perb_bytes) nb = 4;
    else if (ws_size >= 131072 + 2*perb_bytes) nb = 2;

    hipMemsetAsync(d_ws, 0, 102400, stream);
    dim3 blk(256);

    for (int b0 = 0; b0 < 4; b0 += nb) {
        const float* xb = x + (size_t)b0*64*HW;
        const float* yb = y + (size_t)b0*64*HW;
        float* H1 = big;                          // nb*128*HW
        float* H2 = big + (size_t)nb*128*HW;      // nb*64*HW
        float* O  = (float*)d_out + (size_t)b0*64*HW;   // nb*64*HW (d_out as scratch/v)
        float* Q1 = H1;
        float* Q2 = H1 + (size_t)nb*64*HW;
        float* stK = statsKV + b0*4;
        float* stQ = statsQ  + b0*4;
        float* ssk = sumsq_k + b0*64;
        float* ssq = sumsq_q + b0*64;
        float* arw = attn_raw + b0*1024;
        float* atn = attn     + b0*1024;
        float* Mb  = Mw       + b0*4096;

        dim3 gconv(256, nb);
        dim3 gdw(4, 16, nb*64);
        dim3 ggn(64, 64, nb);

        // ---- kv chain ----
        conv1x1_v2<64><<<gconv, blk, 0, stream>>>(yb, 64, kv_w,       0, nullptr, H1, 128, 0,  nullptr, 0);
        conv1x1_v2<64><<<gconv, blk, 0, stream>>>(yb, 64, kv_w+64*64, 0, nullptr, H1, 128, 64, nullptr, 0);
        dwconv_v2<5,1><<<gdw, blk, 0, stream>>>(H1, 128, 0,  kv_c0_w, kv_c0_b, 0,  H2, 64, 0);
        dwconv_v2<5,1><<<gdw, blk, 0, stream>>>(H1, 128, 64, kv_c0_w, kv_c0_b, 64, O,  64, 0);
        dwconv_v2<3,3><<<gdw, blk, 0, stream>>>(H2, 64, 0, kv_cs_w, kv_cs_b, 0,  H1, 128, 0);
        dwconv_v2<3,3><<<gdw, blk, 0, stream>>>(O,  64, 0, kv_cs_w, kv_cs_b, 64, H1, 128, 64);
        conv1x1_v2<128><<<gconv, blk, 0, stream>>>(H1, 128, kv_c1_w,        0, kv_c1_b,    H2, 64, 0, stK,   0);
        conv1x1_v2<128><<<gconv, blk, 0, stream>>>(H1, 128, kv_c1_w+64*128, 0, kv_c1_b+64, O,  64, 0, stK+2, 0);
        gn_apply_v2<<<ggn, blk, 0, stream>>>(H2, stK,   kv_gn_g,    kv_gn_b,    ssk,     1000, 64.f*HW);
        gn_apply_v2<<<ggn, blk, 0, stream>>>(O,  stK+2, kv_gn_g+64, kv_gn_b+64, nullptr, 1000, 64.f*HW);

        // ---- q chain (reuses H1 after kv c1 consumed it) ----
        conv1x1_v2<64><<<gconv, blk, 0, stream>>>(xb, 64, q_w, 0, nullptr, Q1, 64, 0, nullptr, 0);
        dwconv_v2<5,1><<<gdw, blk, 0, stream>>>(Q1, 64, 0, q_c0_w, q_c0_b, 0, Q2, 64, 0);
        dwconv_v2<3,3><<<gdw, blk, 0, stream>>>(Q2, 64, 0, q_cs_w, q_cs_b, 0, Q1, 64, 0);
        conv1x1_v2<64><<<gconv, blk, 0, stream>>>(Q1, 64, q_c1_w, 0, q_c1_b, Q2, 64, 0, stQ, -1);
        gn_apply_v2<<<ggn, blk, 0, stream>>>(Q2, stQ, q_gn_g, q_gn_b, ssq, 32, 32.f*HW);

        // ---- attention + proj fold ----
        attn_dot_v2<<<dim3(128,4,nb), blk, 0, stream>>>(Q2, H2, arw);
        attn_softmax_v2<<<dim3(4,nb), blk, 0, stream>>>(arw, ssq, ssk, temp, atn);
        build_m_v2<<<dim3(nb), blk, 0, stream>>>(atn, proj_w, Mb);

        // ---- out = M[b] @ v, in-place on d_out (reads LDS-staged before writes) ----
        conv1x1_v2<64><<<gconv, blk, 0, stream>>>(O, 64, Mb, 4096, nullptr,
                                                  (float*)d_out + (size_t)b0*64*HW, 64, 0, nullptr, 0);
    }
}

// Round 4
// 1056.484 us; speedup vs baseline: 1.7451x; 1.1784x over previous
//
#include <hip/hip_runtime.h>

#define HW 65536
#define IMG 256

__device__ __forceinline__ float hsum4(float4 v) { return v.x + v.y + v.z + v.w; }
__device__ __forceinline__ float lrelu(float v) { return v >= 0.f ? v : 0.2f * v; }

// ---------------- 1x1 conv, no LDS: direct coalesced loads, deep pipelining ----------------
// grid: (256 pixel-tiles, nb), block 256. Wave wv owns co0=wv*16 (wave-uniform -> scalar weights).
// stats != null (and !GNIN): fused GroupNorm partial sum/sumsq of raw outputs via atomics.
// GNIN: apply per-input-channel GN affine + leaky-relu while reading (single group),
//       using gstats (pre-offset, stride 4/batch), g_gamma/g_beta at g_coff.
template<int CIT, bool GNIN>
__global__ __launch_bounds__(256, 4)
void conv1x1_v3(const float* __restrict__ in, int in_cs,
                const float* __restrict__ w, int w_bstride,
                const float* __restrict__ bias,
                float* __restrict__ out, int out_cs, int out_coff,
                float* __restrict__ stats, int gsel,
                const float* __restrict__ gstats,
                const float* __restrict__ g_gamma, const float* __restrict__ g_beta,
                int g_coff, float g_Nf)
{
    const int b  = blockIdx.y;
    const int j  = threadIdx.x & 63;
    const int wv = __builtin_amdgcn_readfirstlane((int)(threadIdx.x >> 6));
    const int co0 = wv * 16;
    const int q0 = blockIdx.x * 64;
    const float4* in4 = (const float4*)in + (size_t)b * in_cs * (HW/4) + q0 + j;
    const float* wb = w + (size_t)b * w_bstride;

    float gmean = 0.f, grstd = 0.f;
    if (GNIN) {
        gmean = gstats[b*4] / g_Nf;
        float var = gstats[b*4 + 1] / g_Nf - gmean * gmean;
        grstd = rsqrtf(var + 1e-5f);
    }

    float4 acc[16];
    #pragma unroll
    for (int k = 0; k < 16; ++k) {
        float bv = bias ? bias[co0 + k] : 0.f;
        acc[k] = make_float4(bv, bv, bv, bv);
    }

    #pragma unroll 4
    for (int ci = 0; ci < CIT; ++ci) {
        float4 x = in4[(size_t)ci * (HW/4)];
        if (GNIN) {
            float A = g_gamma[g_coff + ci] * grstd;
            float B = g_beta[g_coff + ci] - gmean * A;
            x.x = lrelu(fmaf(x.x, A, B));
            x.y = lrelu(fmaf(x.y, A, B));
            x.z = lrelu(fmaf(x.z, A, B));
            x.w = lrelu(fmaf(x.w, A, B));
        }
        const float* wr = wb + ci;
        #pragma unroll
        for (int k = 0; k < 16; ++k) {
            float wk = wr[(size_t)(co0 + k) * CIT];
            acc[k].x = fmaf(wk, x.x, acc[k].x);
            acc[k].y = fmaf(wk, x.y, acc[k].y);
            acc[k].z = fmaf(wk, x.z, acc[k].z);
            acc[k].w = fmaf(wk, x.w, acc[k].w);
        }
    }

    if (!GNIN && stats) {
        float s = 0.f, ss = 0.f;
        #pragma unroll
        for (int k = 0; k < 16; ++k) {
            s  += acc[k].x + acc[k].y + acc[k].z + acc[k].w;
            ss += acc[k].x*acc[k].x + acc[k].y*acc[k].y
                + acc[k].z*acc[k].z + acc[k].w*acc[k].w;
        }
        #pragma unroll
        for (int o = 32; o; o >>= 1) { s += __shfl_down(s, o, 64); ss += __shfl_down(ss, o, 64); }
        if (j == 0) {
            const int g = (gsel < 0) ? (co0 >= 32 ? 1 : 0) : 0;
            float* st = stats + (size_t)b*4 + g*2;
            atomicAdd(st,     s);
            atomicAdd(st + 1, ss);
        }
    }

    __syncthreads();   // in-place safety: all global reads of this block precede any write

    float4* out4 = (float4*)out + ((size_t)b * out_cs + out_coff) * (HW/4) + q0 + j;
    #pragma unroll
    for (int k = 0; k < 16; ++k)
        out4[(size_t)(co0 + k) * (HW/4)] = acc[k];
}

// ---------------- depthwise conv (5x5 pad2 / 3x3 dil3 pad3), 64 channels per dispatch ----------------
// grid: (4, 16, nb*64), block 256; thread computes 4 px of one row.
template<int TAPS, int DIL>
__global__ __launch_bounds__(256)
void dwconv_v2(const float* __restrict__ in, int in_cs, int in_coff,
               const float* __restrict__ wt, const float* __restrict__ bias, int w_coff,
               float* __restrict__ out, int out_cs, int out_coff)
{
    constexpr int HALO = DIL * (TAPS/2);
    constexpr int TW = 64, TH = 16;
    constexpr int LW = TW + 2*HALO;
    constexpr int LH = TH + 2*HALO;
    constexpr int RS = (LW + 3) & ~3;
    __shared__ float Xs[LH * RS];
    const int z = blockIdx.z;
    const int c = z & 63, b = z >> 6;
    const int x0 = blockIdx.x * TW, y0 = blockIdx.y * TH;
    const float* ip = in + ((size_t)b*in_cs + in_coff + c) * HW;
    const int cw = w_coff + c;
    float wk[TAPS*TAPS];
    #pragma unroll
    for (int i = 0; i < TAPS*TAPS; ++i) wk[i] = wt[cw*TAPS*TAPS + i];
    const float bv = bias[cw];
    for (int idx = threadIdx.x; idx < LH*LW; idx += 256) {
        int ly = idx / LW, lx = idx - ly*LW;
        int gy = y0 + ly - HALO, gx = x0 + lx - HALO;
        float v = 0.f;
        if (gy >= 0 && gy < IMG && gx >= 0 && gx < IMG)
            v = ip[gy*IMG + gx];
        Xs[ly*RS + lx] = v;
    }
    __syncthreads();
    const int qx = (threadIdx.x & 15) * 4;
    const int ly = threadIdx.x >> 4;
    float o0 = bv, o1 = bv, o2 = bv, o3 = bv;
    #pragma unroll
    for (int ky = 0; ky < TAPS; ++ky) {
        const float* row = &Xs[(ly + ky*DIL)*RS + qx];
        float win[(TAPS-1)*DIL + 4];
        #pragma unroll
        for (int i = 0; i < (TAPS-1)*DIL + 4; ++i) win[i] = row[i];
        #pragma unroll
        for (int kx = 0; kx < TAPS; ++kx) {
            float wv_ = wk[ky*TAPS + kx];
            o0 = fmaf(wv_, win[kx*DIL + 0], o0);
            o1 = fmaf(wv_, win[kx*DIL + 1], o1);
            o2 = fmaf(wv_, win[kx*DIL + 2], o2);
            o3 = fmaf(wv_, win[kx*DIL + 3], o3);
        }
    }
    *(float4*)(out + ((size_t)b*out_cs + out_coff + c) * HW + (size_t)(y0 + ly)*IMG + x0 + qx) =
        make_float4(o0, o1, o2, o3);
}

// ---------------- attention raw dots, with GN+leaky fused on q,k + post-act sumsq ----------------
// grid: (128, 4, nb), block 256. LDS transposed [t][c] for conflict-free b128 reads.
__global__ __launch_bounds__(256)
void attn_dot_v3(const float* __restrict__ q, const float* __restrict__ k,
                 const float* __restrict__ stQ, const float* __restrict__ stK,
                 const float* __restrict__ qg, const float* __restrict__ qb,
                 const float* __restrict__ kg, const float* __restrict__ kb,
                 float* __restrict__ attn_raw,
                 float* __restrict__ ssq, float* __restrict__ ssk)
{
    __shared__ float4 qs[2048], ks[2048];   // 32 KiB each
    __shared__ float sred[512];
    const int h = blockIdx.y, b = blockIdx.z;
    const int t0 = blockIdx.x * 128;
    const int cc = threadIdx.x & 15;
    const int ch = h*16 + cc;               // channel index within the 64-ch tensor

    // q GN params: 64 ch in 2 groups of 32
    const int gq = (ch >= 32) ? 1 : 0;
    float mq = stQ[b*4 + gq*2] / (32.f * HW);
    float vq = stQ[b*4 + gq*2 + 1] / (32.f * HW) - mq*mq;
    const float Aq = qg[ch] * rsqrtf(vq + 1e-5f);
    const float Bq = qb[ch] - mq * Aq;
    // k channels are kv-c1 channels 0..63 -> all in kv group 0 (of 64 ch)
    float mk = stK[b*4] / (64.f * HW);
    float vk = stK[b*4 + 1] / (64.f * HW) - mk*mk;
    const float Ak = kg[ch] * rsqrtf(vk + 1e-5f);
    const float Bk = kb[ch] - mk * Ak;

    const float4* q4 = (const float4*)q + ((size_t)b*64 + ch) * (HW/4) + t0;
    const float4* k4 = (const float4*)k + ((size_t)b*64 + ch) * (HW/4) + t0;
    float sq_acc = 0.f, sk_acc = 0.f;
    #pragma unroll
    for (int s = 0; s < 8; ++s) {
        int t = (threadIdx.x >> 4) + s*16;
        float4 v = q4[t];
        v.x = lrelu(fmaf(v.x, Aq, Bq)); v.y = lrelu(fmaf(v.y, Aq, Bq));
        v.z = lrelu(fmaf(v.z, Aq, Bq)); v.w = lrelu(fmaf(v.w, Aq, Bq));
        sq_acc += v.x*v.x + v.y*v.y + v.z*v.z + v.w*v.w;
        qs[t*16 + cc] = v;
        float4 u = k4[t];
        u.x = lrelu(fmaf(u.x, Ak, Bk)); u.y = lrelu(fmaf(u.y, Ak, Bk));
        u.z = lrelu(fmaf(u.z, Ak, Bk)); u.w = lrelu(fmaf(u.w, Ak, Bk));
        sk_acc += u.x*u.x + u.y*u.y + u.z*u.z + u.w*u.w;
        ks[t*16 + cc] = u;
    }
    sred[threadIdx.x]       = sq_acc;
    sred[256 + threadIdx.x] = sk_acc;
    __syncthreads();

    const int p   = threadIdx.x & 63;
    const int sub = threadIdx.x >> 6;
    const int c0 = (p >> 3) << 1, d0 = (p & 7) << 1;
    float4 a00 = make_float4(0,0,0,0), a01 = a00, a10 = a00, a11 = a00;
    #pragma unroll
    for (int i = 0; i < 32; ++i) {
        int t = sub*32 + i;
        float4 qa = qs[t*16 + c0], qb_ = qs[t*16 + c0 + 1];
        float4 ka = ks[t*16 + d0], kb_ = ks[t*16 + d0 + 1];
        a00.x = fmaf(qa.x, ka.x, a00.x); a00.y = fmaf(qa.y, ka.y, a00.y);
        a00.z = fmaf(qa.z, ka.z, a00.z); a00.w = fmaf(qa.w, ka.w, a00.w);
        a01.x = fmaf(qa.x, kb_.x, a01.x); a01.y = fmaf(qa.y, kb_.y, a01.y);
        a01.z = fmaf(qa.z, kb_.z, a01.z); a01.w = fmaf(qa.w, kb_.w, a01.w);
        a10.x = fmaf(qb_.x, ka.x, a10.x); a10.y = fmaf(qb_.y, ka.y, a10.y);
        a10.z = fmaf(qb_.z, ka.z, a10.z); a10.w = fmaf(qb_.w, ka.w, a10.w);
        a11.x = fmaf(qb_.x, kb_.x, a11.x); a11.y = fmaf(qb_.y, kb_.y, a11.y);
        a11.z = fmaf(qb_.z, kb_.z, a11.z); a11.w = fmaf(qb_.w, kb_.w, a11.w);
    }
    float* ar = attn_raw + ((size_t)b*4 + h) * 256;
    atomicAdd(&ar[(c0  )*16 + d0  ], hsum4(a00));
    atomicAdd(&ar[(c0  )*16 + d0+1], hsum4(a01));
    atomicAdd(&ar[(c0+1)*16 + d0  ], hsum4(a10));
    atomicAdd(&ar[(c0+1)*16 + d0+1], hsum4(a11));

    // per-channel post-activation sumsq partials
    if (threadIdx.x < 16) {
        float s = 0.f;
        #pragma unroll
        for (int jj = 0; jj < 16; ++jj) s += sred[threadIdx.x + 16*jj];
        atomicAdd(&ssq[b*64 + h*16 + threadIdx.x], s);
    } else if (threadIdx.x < 32) {
        const int c2 = threadIdx.x - 16;
        float s = 0.f;
        #pragma unroll
        for (int jj = 0; jj < 16; ++jj) s += sred[256 + c2 + 16*jj];
        atomicAdd(&ssk[b*64 + h*16 + c2], s);
    }
}

// ---------------- softmax with l2-norm scaling + temperature ----------------
// grid: (4, nb), block 256 = 16x16.
__global__ __launch_bounds__(256)
void attn_softmax_v2(const float* __restrict__ attn_raw,
                     const float* __restrict__ ssq, const float* __restrict__ ssk,
                     const float* __restrict__ temp, float* __restrict__ attn)
{
    const int h = blockIdx.x, b = blockIdx.y;
    const int c = threadIdx.x >> 4, d = threadIdx.x & 15;
    const float nq = fmaxf(sqrtf(ssq[b*64 + h*16 + c]), 1e-12f);
    const float nk = fmaxf(sqrtf(ssk[b*64 + h*16 + d]), 1e-12f);
    float logit = attn_raw[((size_t)b*4 + h)*256 + c*16 + d] / (nq * nk) * temp[h];
    float m = logit;
    #pragma unroll
    for (int o = 8; o; o >>= 1) m = fmaxf(m, __shfl_xor(m, o, 16));
    float e = expf(logit - m);
    float s = e;
    #pragma unroll
    for (int o = 8; o; o >>= 1) s += __shfl_xor(s, o, 16);
    attn[((size_t)b*4 + h)*256 + c*16 + d] = e / s;
}

// ---------------- M[b] = proj . blockdiag(attn[b]) ----------------
// grid: nb, block 256.
__global__ __launch_bounds__(256)
void build_m_v2(const float* __restrict__ attn, const float* __restrict__ proj_w,
                float* __restrict__ M)
{
    const int b = blockIdx.x;
    for (int i = threadIdx.x; i < 4096; i += 256) {
        int co = i >> 6, ci = i & 63;
        int h = ci >> 4, d = ci & 15;
        float s = 0.f;
        #pragma unroll
        for (int cc = 0; cc < 16; ++cc)
            s += proj_w[co*64 + h*16 + cc] * attn[((size_t)b*4 + h)*256 + cc*16 + d];
        M[(size_t)b*4096 + i] = s;
    }
}

extern "C" void kernel_launch(void* const* d_in, const int* in_sizes, int n_in,
                              void* d_out, int out_size, void* d_ws, size_t ws_size,
                              hipStream_t stream)
{
    const float* x       = (const float*)d_in[0];
    const float* y       = (const float*)d_in[1];
    const float* kv_w    = (const float*)d_in[2];
    const float* q_w     = (const float*)d_in[3];
    const float* proj_w  = (const float*)d_in[4];
    const float* kv_c0_w = (const float*)d_in[5];
    const float* kv_c0_b = (const float*)d_in[6];
    const float* kv_cs_w = (const float*)d_in[7];
    const float* kv_cs_b = (const float*)d_in[8];
    const float* kv_c1_w = (const float*)d_in[9];
    const float* kv_c1_b = (const float*)d_in[10];
    const float* kv_gn_g = (const float*)d_in[11];
    const float* kv_gn_b = (const float*)d_in[12];
    const float* q_c0_w  = (const float*)d_in[13];
    const float* q_c0_b  = (const float*)d_in[14];
    const float* q_cs_w  = (const float*)d_in[15];
    const float* q_cs_b  = (const float*)d_in[16];
    const float* q_c1_w  = (const float*)d_in[17];
    const float* q_c1_b  = (const float*)d_in[18];
    const float* q_gn_g  = (const float*)d_in[19];
    const float* q_gn_b  = (const float*)d_in[20];
    const float* temp    = (const float*)d_in[21];

    float* ws       = (float*)d_ws;
    float* statsKV  = ws;            // 4/batch  -> 16
    float* statsQ   = ws + 16;
    float* sumsq_k  = ws + 32;       // 64/batch -> 256
    float* sumsq_q  = ws + 288;
    float* attn_raw = ws + 544;      // 1024/batch -> 4096
    float* attn     = ws + 4640;
    float* Mw       = ws + 8736;     // 4096/batch -> 16384 (end 25120)
    float* big      = (float*)((char*)d_ws + 131072);

    // per-batch big-buffer need: H1 = 128*HW, H2 = 64*HW floats (48 MiB); O lives in d_out
    const size_t perb_bytes = (size_t)192 * HW * 4;
    int nb = 1;
    if      (ws_size >= 131072 + 4*perb_bytes) nb = 4;
    else if (ws_size >= 131072 + 2*perb_bytes) nb = 2;

    hipMemsetAsync(d_ws, 0, 102400, stream);
    dim3 blk(256);

    for (int b0 = 0; b0 < 4; b0 += nb) {
        const float* xb = x + (size_t)b0*64*HW;
        const float* yb = y + (size_t)b0*64*HW;
        float* H1 = big;                          // nb*128*HW
        float* H2 = big + (size_t)nb*128*HW;      // nb*64*HW
        float* O  = (float*)d_out + (size_t)b0*64*HW;   // nb*64*HW (d_out as scratch/v)
        float* Q1 = H1;
        float* Q2 = H1 + (size_t)nb*64*HW;
        float* stK = statsKV + b0*4;
        float* stQ = statsQ  + b0*4;
        float* ssk = sumsq_k + b0*64;
        float* ssq = sumsq_q + b0*64;
        float* arw = attn_raw + b0*1024;
        float* atn = attn     + b0*1024;
        float* Mb  = Mw       + b0*4096;

        dim3 gconv(256, nb);
        dim3 gdw(4, 16, nb*64);

        // ---- kv chain: 1x1 (k-pre, v-pre) -> dw5x5 -> dw3x3d3 -> 1x1 c1 (raw + fused GN stats) ----
        conv1x1_v3<64,false><<<gconv, blk, 0, stream>>>(yb, 64, kv_w,       0, nullptr, H1, 128, 0,
                                                        nullptr, 0, nullptr, nullptr, nullptr, 0, 0.f);
        conv1x1_v3<64,false><<<gconv, blk, 0, stream>>>(yb, 64, kv_w+64*64, 0, nullptr, H1, 128, 64,
                                                        nullptr, 0, nullptr, nullptr, nullptr, 0, 0.f);
        dwconv_v2<5,1><<<gdw, blk, 0, stream>>>(H1, 128, 0,  kv_c0_w, kv_c0_b, 0,  H2, 64, 0);
        dwconv_v2<5,1><<<gdw, blk, 0, stream>>>(H1, 128, 64, kv_c0_w, kv_c0_b, 64, O,  64, 0);
        dwconv_v2<3,3><<<gdw, blk, 0, stream>>>(H2, 64, 0, kv_cs_w, kv_cs_b, 0,  H1, 128, 0);
        dwconv_v2<3,3><<<gdw, blk, 0, stream>>>(O,  64, 0, kv_cs_w, kv_cs_b, 64, H1, 128, 64);
        conv1x1_v3<128,false><<<gconv, blk, 0, stream>>>(H1, 128, kv_c1_w,        0, kv_c1_b,    H2, 64, 0,
                                                         stK,   0, nullptr, nullptr, nullptr, 0, 0.f);
        conv1x1_v3<128,false><<<gconv, blk, 0, stream>>>(H1, 128, kv_c1_w+64*128, 0, kv_c1_b+64, O,  64, 0,
                                                         stK+2, 0, nullptr, nullptr, nullptr, 0, 0.f);

        // ---- q chain (reuses H1 after kv c1 consumed it) ----
        conv1x1_v3<64,false><<<gconv, blk, 0, stream>>>(xb, 64, q_w, 0, nullptr, Q1, 64, 0,
                                                        nullptr, 0, nullptr, nullptr, nullptr, 0, 0.f);
        dwconv_v2<5,1><<<gdw, blk, 0, stream>>>(Q1, 64, 0, q_c0_w, q_c0_b, 0, Q2, 64, 0);
        dwconv_v2<3,3><<<gdw, blk, 0, stream>>>(Q2, 64, 0, q_cs_w, q_cs_b, 0, Q1, 64, 0);
        conv1x1_v3<64,false><<<gconv, blk, 0, stream>>>(Q1, 64, q_c1_w, 0, q_c1_b, Q2, 64, 0,
                                                        stQ, -1, nullptr, nullptr, nullptr, 0, 0.f);

        // ---- attention: GN+leaky fused into q/k staging; sumsq accumulated there ----
        attn_dot_v3<<<dim3(128,4,nb), blk, 0, stream>>>(Q2, H2, stQ, stK,
                                                        q_gn_g, q_gn_b, kv_gn_g, kv_gn_b,
                                                        arw, ssq, ssk);
        attn_softmax_v2<<<dim3(4,nb), blk, 0, stream>>>(arw, ssq, ssk, temp, atn);
        build_m_v2<<<dim3(nb), blk, 0, stream>>>(atn, proj_w, Mb);

        // ---- out = M[b] @ leaky(GN(v)), in-place on d_out; GN fused on input rows ----
        conv1x1_v3<64,true><<<gconv, blk, 0, stream>>>(O, 64, Mw + b0*4096, 4096, nullptr,
                                                       (float*)d_out + (size_t)b0*64*HW, 64, 0,
                                                       nullptr, 0, stK+2, kv_gn_g, kv_gn_b, 64, 64.f*HW);
    }
}